// Round 1
// baseline (164.254 us; speedup 1.0000x reference)
//
#include <hip/hip_runtime.h>
#include <stdint.h>

#define SEQ 2048
#define DM 1024
#define NH 16
#define DH 64
#define LN_EPS 1e-5f

typedef __bf16 bf16x8 __attribute__((ext_vector_type(8)));
typedef float f32x4 __attribute__((ext_vector_type(4)));
typedef unsigned short u16;
typedef unsigned short u16x8 __attribute__((ext_vector_type(8)));

__device__ __forceinline__ u16 f2bf(float f) {
  unsigned int u = __float_as_uint(f);
  unsigned int r = (u + 0x7fffu + ((u >> 16) & 1u)) >> 16;
  return (u16)r;
}

#define GLD_LDS16(gp, lp) __builtin_amdgcn_global_load_lds( \
  (const __attribute__((address_space(1))) void*)(gp),      \
  (__attribute__((address_space(3))) void*)(lp), 16, 0, 0)

// ---------------- f32 -> bf16 convert ----------------
__global__ __launch_bounds__(256) void k_f2bf(const float* __restrict__ in,
                                              u16* __restrict__ out, int n4) {
  int i = blockIdx.x * 256 + threadIdx.x;
  if (i >= n4) return;
  float4 v = reinterpret_cast<const float4*>(in)[i];
  ushort4 o;
  o.x = f2bf(v.x); o.y = f2bf(v.y); o.z = f2bf(v.z); o.w = f2bf(v.w);
  reinterpret_cast<ushort4*>(out)[i] = o;
}

// ---------------- GEMM: C = A(bf16 MxK) * B(bf16 NxK)^T + bias ----------------
// EPI 0: out bf16.  EPI 1: out f32 = res + acc + bias (residual fused).
template <int EPI>
__global__ __launch_bounds__(256)
void k_gemm_bt(const u16* __restrict__ A, const u16* __restrict__ B,
               const float* __restrict__ bias, const float* __restrict__ res,
               u16* __restrict__ outb, float* __restrict__ outf,
               int M, int N, int K) {
  __shared__ u16 Alds[2][128][32];
  __shared__ u16 Blds[2][128][32];
  const int tid = threadIdx.x;
  const int w = tid >> 6, l = tid & 63, lg = l >> 4, lr = l & 15;
  const int wr = w >> 1, wc = w & 1;
  const int m0 = blockIdx.y * 128, n0 = blockIdx.x * 128;
  const int KT = K >> 5;

  f32x4 acc[4][4] = {};

  auto stage = [&](int buf, int kt) {
    const int k0 = kt << 5;
#pragma unroll
    for (int p = 0; p < 2; ++p) {
      const int rbase = w * 32 + p * 16;
      const int row = rbase + (l >> 2);
      const int col = (l & 3) * 8;
      GLD_LDS16(A + (size_t)(m0 + row) * K + k0 + col, &Alds[buf][rbase][0]);
      GLD_LDS16(B + (size_t)(n0 + row) * K + k0 + col, &Blds[buf][rbase][0]);
    }
  };

  auto compute = [&](int buf) {
    bf16x8 af[4], bfr[4];
#pragma unroll
    for (int mi = 0; mi < 4; ++mi)
      af[mi] = *reinterpret_cast<const bf16x8*>(&Alds[buf][wr * 64 + mi * 16 + lr][lg * 8]);
#pragma unroll
    for (int ni = 0; ni < 4; ++ni)
      bfr[ni] = *reinterpret_cast<const bf16x8*>(&Blds[buf][wc * 64 + ni * 16 + lr][lg * 8]);
#pragma unroll
    for (int mi = 0; mi < 4; ++mi)
#pragma unroll
      for (int ni = 0; ni < 4; ++ni)
        acc[mi][ni] = __builtin_amdgcn_mfma_f32_16x16x32_bf16(af[mi], bfr[ni], acc[mi][ni], 0, 0, 0);
  };

  stage(0, 0);
  __syncthreads();
  for (int kt = 0; kt < KT; ++kt) {
    const int cur = kt & 1;
    if (kt + 1 < KT) stage(cur ^ 1, kt + 1);
    compute(cur);
    __syncthreads();
  }

#pragma unroll
  for (int ni = 0; ni < 4; ++ni) {
    const int n = n0 + wc * 64 + ni * 16 + lr;
    const float bn = bias[n];
#pragma unroll
    for (int mi = 0; mi < 4; ++mi) {
#pragma unroll
      for (int r = 0; r < 4; ++r) {
        const int m = m0 + wr * 64 + mi * 16 + lg * 4 + r;
        const float v = acc[mi][ni][r] + bn;
        if (EPI == 0) {
          outb[(size_t)m * N + n] = f2bf(v);
        } else {
          outf[(size_t)m * N + n] = res[(size_t)m * N + n] + v;
        }
      }
    }
  }
}

// ---------------- flash attention ----------------
// qkv: [2048][3072] bf16 (q | k | v each 1024 cols). out: [2048][1024] bf16.
__global__ __launch_bounds__(256)
void k_attn(const u16* __restrict__ qkv, u16* __restrict__ attn_out) {
  __shared__ u16 Klds[64][64];
  __shared__ u16 Vt[64][64];
  __shared__ u16 Plds[4][16][64];
  const int tid = threadIdx.x;
  const int w = tid >> 6, l = tid & 63, lg = l >> 4, lr = l & 15;
  const int qb = blockIdx.x, h = blockIdx.y;
  const int hq = h * 64, hk = 1024 + h * 64, hv = 2048 + h * 64;

  // Q A-fragments: lane l holds Q[row=lr][k = kk*32 + lg*8 + j]
  bf16x8 qf[2];
  {
    const size_t qrow = (size_t)(qb * 64 + w * 16 + lr) * 3072;
    qf[0] = *reinterpret_cast<const bf16x8*>(&qkv[qrow + hq + lg * 8]);
    qf[1] = *reinterpret_cast<const bf16x8*>(&qkv[qrow + hq + 32 + lg * 8]);
  }

  f32x4 oacc[4] = {};
  float mrun[4] = {-1e30f, -1e30f, -1e30f, -1e30f};
  float lrun[4] = {0.f, 0.f, 0.f, 0.f};

  for (int kb = 0; kb < SEQ / 64; ++kb) {
    // stage K row-major, V transposed
    {
      const int row = tid >> 2, c0 = (tid & 3) * 16;
      const size_t grow = (size_t)(kb * 64 + row) * 3072;
      *reinterpret_cast<u16x8*>(&Klds[row][c0]) =
          *reinterpret_cast<const u16x8*>(&qkv[grow + hk + c0]);
      *reinterpret_cast<u16x8*>(&Klds[row][c0 + 8]) =
          *reinterpret_cast<const u16x8*>(&qkv[grow + hk + c0 + 8]);
      u16x8 v0 = *reinterpret_cast<const u16x8*>(&qkv[grow + hv + c0]);
      u16x8 v1 = *reinterpret_cast<const u16x8*>(&qkv[grow + hv + c0 + 8]);
#pragma unroll
      for (int j = 0; j < 8; ++j) {
        Vt[c0 + j][row] = v0[j];
        Vt[c0 + 8 + j][row] = v1[j];
      }
    }
    __syncthreads();

    // scores: S[16 q][64 kc] per wave
    f32x4 s[4];
#pragma unroll
    for (int nt = 0; nt < 4; ++nt) {
      bf16x8 kf0 = *reinterpret_cast<const bf16x8*>(&Klds[nt * 16 + lr][lg * 8]);
      bf16x8 kf1 = *reinterpret_cast<const bf16x8*>(&Klds[nt * 16 + lr][32 + lg * 8]);
      f32x4 a = {};
      a = __builtin_amdgcn_mfma_f32_16x16x32_bf16(qf[0], kf0, a, 0, 0, 0);
      a = __builtin_amdgcn_mfma_f32_16x16x32_bf16(qf[1], kf1, a, 0, 0, 0);
      s[nt] = a * 0.125f;  // 1/sqrt(64)
    }

    // online softmax (row = lg*4 + r, cols across lr + nt)
    float al[4];
#pragma unroll
    for (int r = 0; r < 4; ++r) {
      float mx = fmaxf(fmaxf(s[0][r], s[1][r]), fmaxf(s[2][r], s[3][r]));
#pragma unroll
      for (int msk = 1; msk < 16; msk <<= 1) mx = fmaxf(mx, __shfl_xor(mx, msk));
      const float mn = fmaxf(mrun[r], mx);
      al[r] = __expf(mrun[r] - mn);
      mrun[r] = mn;
    }
    float rs[4] = {0.f, 0.f, 0.f, 0.f};
#pragma unroll
    for (int nt = 0; nt < 4; ++nt) {
#pragma unroll
      for (int r = 0; r < 4; ++r) {
        const float p = __expf(s[nt][r] - mrun[r]);
        rs[r] += p;
        Plds[w][lg * 4 + r][nt * 16 + lr] = f2bf(p);
      }
    }
#pragma unroll
    for (int r = 0; r < 4; ++r) {
      float t = rs[r];
#pragma unroll
      for (int msk = 1; msk < 16; msk <<= 1) t += __shfl_xor(t, msk);
      lrun[r] = lrun[r] * al[r] + t;
#pragma unroll
      for (int nd = 0; nd < 4; ++nd) oacc[nd][r] *= al[r];
    }

    // PV: O[16 q][64 d] += P[16][64] * V[64][64]
#pragma unroll
    for (int kk = 0; kk < 2; ++kk) {
      bf16x8 pa = *reinterpret_cast<const bf16x8*>(&Plds[w][lr][kk * 32 + lg * 8]);
#pragma unroll
      for (int nd = 0; nd < 4; ++nd) {
        bf16x8 vf = *reinterpret_cast<const bf16x8*>(&Vt[nd * 16 + lr][kk * 32 + lg * 8]);
        oacc[nd] = __builtin_amdgcn_mfma_f32_16x16x32_bf16(pa, vf, oacc[nd], 0, 0, 0);
      }
    }
    __syncthreads();
  }

#pragma unroll
  for (int r = 0; r < 4; ++r) {
    const float inv = 1.f / lrun[r];
    const size_t qrow = (size_t)(qb * 64 + w * 16 + lg * 4 + r) * DM;
#pragma unroll
    for (int nd = 0; nd < 4; ++nd)
      attn_out[qrow + h * 64 + nd * 16 + lr] = f2bf(oacc[nd][r] * inv);
  }
}

// ---------------- in-place row LayerNorm ----------------
__global__ __launch_bounds__(256)
void k_ln(float* __restrict__ x, const float* __restrict__ gamma,
          const float* __restrict__ beta) {
  const int row = blockIdx.x, tid = threadIdx.x;
  float4 v = reinterpret_cast<const float4*>(x + (size_t)row * DM)[tid];
  float s = v.x + v.y + v.z + v.w;
  float q = v.x * v.x + v.y * v.y + v.z * v.z + v.w * v.w;
#pragma unroll
  for (int m = 1; m < 64; m <<= 1) { s += __shfl_xor(s, m); q += __shfl_xor(q, m); }
  __shared__ float sh[8];
  const int w = tid >> 6;
  if ((tid & 63) == 0) { sh[w] = s; sh[4 + w] = q; }
  __syncthreads();
  s = sh[0] + sh[1] + sh[2] + sh[3];
  q = sh[4] + sh[5] + sh[6] + sh[7];
  const float mu = s * (1.f / 1024.f);
  const float var = q * (1.f / 1024.f) - mu * mu;
  const float rstd = rsqrtf(var + LN_EPS);
  float4 g = reinterpret_cast<const float4*>(gamma)[tid];
  float4 b = reinterpret_cast<const float4*>(beta)[tid];
  float4 o;
  o.x = (v.x - mu) * rstd * g.x + b.x;
  o.y = (v.y - mu) * rstd * g.y + b.y;
  o.z = (v.z - mu) * rstd * g.z + b.z;
  o.w = (v.w - mu) * rstd * g.w + b.w;
  reinterpret_cast<float4*>(x + (size_t)row * DM)[tid] = o;
}

extern "C" void kernel_launch(void* const* d_in, const int* in_sizes, int n_in,
                              void* d_out, int out_size, void* d_ws, size_t ws_size,
                              hipStream_t stream) {
  const float* h     = (const float*)d_in[0];
  const float* Wqkv  = (const float*)d_in[1];
  const float* bqkv  = (const float*)d_in[2];
  const float* Wout  = (const float*)d_in[3];
  const float* bout  = (const float*)d_in[4];
  const float* gamma = (const float*)d_in[5];
  const float* beta  = (const float*)d_in[6];
  float* out = (float*)d_out;

  char* ws = (char*)d_ws;
  u16* h_bf    = (u16*)(ws);                          // 2048*1024*2 = 4 MB
  u16* Wqkv_bf = (u16*)(ws + (size_t)4 * 1024 * 1024);   // 6 MB
  u16* Wout_bf = (u16*)(ws + (size_t)10 * 1024 * 1024);  // 2 MB
  u16* qkv_bf  = (u16*)(ws + (size_t)12 * 1024 * 1024);  // 12 MB
  u16* attn_bf = (u16*)(ws + (size_t)24 * 1024 * 1024);  // 4 MB

  k_f2bf<<<2048, 256, 0, stream>>>(h, h_bf, SEQ * DM / 4);
  k_f2bf<<<3072, 256, 0, stream>>>(Wqkv, Wqkv_bf, 3 * DM * DM / 4);
  k_f2bf<<<1024, 256, 0, stream>>>(Wout, Wout_bf, DM * DM / 4);

  k_gemm_bt<0><<<dim3(24, 16), 256, 0, stream>>>(h_bf, Wqkv_bf, bqkv, nullptr,
                                                 qkv_bf, nullptr, SEQ, 3 * DM, DM);

  k_attn<<<dim3(SEQ / 64, NH), 256, 0, stream>>>(qkv_bf, attn_bf);

  k_gemm_bt<1><<<dim3(8, 16), 256, 0, stream>>>(attn_bf, Wout_bf, bout, h,
                                                nullptr, out, SEQ, DM, DM);

  k_ln<<<SEQ, 256, 0, stream>>>(out, gamma, beta);
}

// Round 2
// 141.575 us; speedup vs baseline: 1.1602x; 1.1602x over previous
//
#include <hip/hip_runtime.h>
#include <stdint.h>

#define SEQ 2048
#define DM 1024
#define NH 16
#define DH 64
#define LN_EPS 1e-5f

typedef __bf16 bf16x8 __attribute__((ext_vector_type(8)));
typedef float f32x4 __attribute__((ext_vector_type(4)));
typedef unsigned short u16;
typedef unsigned short u16x8 __attribute__((ext_vector_type(8)));

__device__ __forceinline__ u16 f2bf(float f) {
  unsigned int u = __float_as_uint(f);
  unsigned int r = (u + 0x7fffu + ((u >> 16) & 1u)) >> 16;
  return (u16)r;
}

#define GLD_LDS16(gp, lp) __builtin_amdgcn_global_load_lds( \
  (const __attribute__((address_space(1))) void*)(gp),      \
  (__attribute__((address_space(3))) void*)(lp), 16, 0, 0)

// ---------------- f32 -> bf16 convert ----------------
__global__ __launch_bounds__(256) void k_f2bf(const float* __restrict__ in,
                                              u16* __restrict__ out, int n4) {
  int i = blockIdx.x * 256 + threadIdx.x;
  if (i >= n4) return;
  float4 v = reinterpret_cast<const float4*>(in)[i];
  ushort4 o;
  o.x = f2bf(v.x); o.y = f2bf(v.y); o.z = f2bf(v.z); o.w = f2bf(v.w);
  reinterpret_cast<ushort4*>(out)[i] = o;
}

// ---------------- GEMM: C = A(bf16 MxK) * B(bf16 NxK)^T + bias ----------------
// EPI 1: out f32 = res + acc + bias (residual fused).
// EPI 2: QKV split: n<2048 -> outb[m][n] bf16 ([M][2048] q|k packed);
//        n>=2048  -> outv[(n-2048)][m] bf16 (V transposed, [1024][M]).
template <int EPI>
__global__ __launch_bounds__(256)
void k_gemm_bt(const u16* __restrict__ A, const u16* __restrict__ B,
               const float* __restrict__ bias, const float* __restrict__ res,
               u16* __restrict__ outb, u16* __restrict__ outv,
               float* __restrict__ outf, int M, int N, int K) {
  __shared__ u16 Alds[2][128][32];
  __shared__ u16 Blds[2][128][32];
  const int tid = threadIdx.x;
  const int w = tid >> 6, l = tid & 63, lg = l >> 4, lr = l & 15;
  const int wr = w >> 1, wc = w & 1;
  const int m0 = blockIdx.y * 128, n0 = blockIdx.x * 128;
  const int KT = K >> 5;

  f32x4 acc[4][4] = {};

  auto stage = [&](int buf, int kt) {
    const int k0 = kt << 5;
#pragma unroll
    for (int p = 0; p < 2; ++p) {
      const int rbase = w * 32 + p * 16;
      const int row = rbase + (l >> 2);
      const int col = (l & 3) * 8;
      GLD_LDS16(A + (size_t)(m0 + row) * K + k0 + col, &Alds[buf][rbase][0]);
      GLD_LDS16(B + (size_t)(n0 + row) * K + k0 + col, &Blds[buf][rbase][0]);
    }
  };

  auto compute = [&](int buf) {
    bf16x8 af[4], bfr[4];
#pragma unroll
    for (int mi = 0; mi < 4; ++mi)
      af[mi] = *reinterpret_cast<const bf16x8*>(&Alds[buf][wr * 64 + mi * 16 + lr][lg * 8]);
#pragma unroll
    for (int ni = 0; ni < 4; ++ni)
      bfr[ni] = *reinterpret_cast<const bf16x8*>(&Blds[buf][wc * 64 + ni * 16 + lr][lg * 8]);
#pragma unroll
    for (int mi = 0; mi < 4; ++mi)
#pragma unroll
      for (int ni = 0; ni < 4; ++ni)
        acc[mi][ni] = __builtin_amdgcn_mfma_f32_16x16x32_bf16(af[mi], bfr[ni], acc[mi][ni], 0, 0, 0);
  };

  stage(0, 0);
  __syncthreads();
  for (int kt = 0; kt < KT; ++kt) {
    const int cur = kt & 1;
    if (kt + 1 < KT) stage(cur ^ 1, kt + 1);
    compute(cur);
    __syncthreads();
  }

  if (EPI == 1) {
#pragma unroll
    for (int ni = 0; ni < 4; ++ni) {
      const int n = n0 + wc * 64 + ni * 16 + lr;
      const float bn = bias[n];
#pragma unroll
      for (int mi = 0; mi < 4; ++mi) {
#pragma unroll
        for (int r = 0; r < 4; ++r) {
          const int m = m0 + wr * 64 + mi * 16 + lg * 4 + r;
          const float v = acc[mi][ni][r] + bn;
          outf[(size_t)m * N + n] = res[(size_t)m * N + n] + v;
        }
      }
    }
  } else {  // EPI == 2
    if (n0 < 2048) {
#pragma unroll
      for (int ni = 0; ni < 4; ++ni) {
        const int n = n0 + wc * 64 + ni * 16 + lr;
        const float bn = bias[n];
#pragma unroll
        for (int mi = 0; mi < 4; ++mi) {
#pragma unroll
          for (int r = 0; r < 4; ++r) {
            const int m = m0 + wr * 64 + mi * 16 + lg * 4 + r;
            outb[(size_t)m * 2048 + n] = f2bf(acc[mi][ni][r] + bn);
          }
        }
      }
    } else {
#pragma unroll
      for (int ni = 0; ni < 4; ++ni) {
        const int n = n0 + wc * 64 + ni * 16 + lr;
        const float bn = bias[n];
#pragma unroll
        for (int mi = 0; mi < 4; ++mi) {
          const int mb = m0 + wr * 64 + mi * 16 + lg * 4;
          ushort4 pk;
          pk.x = f2bf(acc[mi][ni][0] + bn);
          pk.y = f2bf(acc[mi][ni][1] + bn);
          pk.z = f2bf(acc[mi][ni][2] + bn);
          pk.w = f2bf(acc[mi][ni][3] + bn);
          *reinterpret_cast<ushort4*>(&outv[(size_t)(n - 2048) * M + mb]) = pk;
        }
      }
    }
  }
}

// ---------------- flash attention ----------------
// qk: [2048][2048] bf16 (q | k each 1024 cols). vt: [1024][2048] bf16 (V^T).
// out: [2048][1024] bf16.
__global__ __launch_bounds__(256)
void k_attn(const u16* __restrict__ qk, const u16* __restrict__ vt,
            u16* __restrict__ attn_out) {
  // K/V tiles: 64 rows x 64 cols bf16 (128 B rows), XOR-swizzled chunk layout.
  __shared__ u16 Klds[2][64 * 64];
  __shared__ u16 Vlds[2][64 * 64];
  __shared__ u16 Plds[4][16][72];  // padded rows: 144 B -> conflict-free A-frag reads
  const int tid = threadIdx.x;
  const int w = tid >> 6, l = tid & 63, lg = l >> 4, lr = l & 15;
  const int qb = blockIdx.x, h = blockIdx.y;

  // Q A-fragments: lane holds Q[row=lr][k = kk*32 + lg*8 + j]
  bf16x8 qf[2];
  {
    const size_t qrow = (size_t)(qb * 64 + w * 16 + lr) * 2048 + h * 64;
    qf[0] = *reinterpret_cast<const bf16x8*>(&qk[qrow + lg * 8]);
    qf[1] = *reinterpret_cast<const bf16x8*>(&qk[qrow + 32 + lg * 8]);
  }

  // stage: linear LDS dest (global_load_lds), inverse-swizzled global source.
  // LDS chunk (row r, c) holds logical chunk c^(r&7) of that row.
  auto stage = [&](int buf, int kb) {
#pragma unroll
    for (int p = 0; p < 2; ++p) {
      const int r = w * 16 + p * 8 + (l >> 3);
      const int sc = (l & 7) ^ (r & 7);
      const u16* ksrc = qk + (size_t)(kb * 64 + r) * 2048 + 1024 + h * 64 + sc * 8;
      GLD_LDS16(ksrc, &Klds[buf][(w * 16 + p * 8) * 64]);
      const u16* vsrc = vt + (size_t)(h * 64 + r) * 2048 + kb * 64 + sc * 8;
      GLD_LDS16(vsrc, &Vlds[buf][(w * 16 + p * 8) * 64]);
    }
  };

  auto kread = [&](int buf, int row, int kbyte) -> bf16x8 {
    const int off = row * 128 + (kbyte ^ ((row & 7) << 4));
    return *reinterpret_cast<const bf16x8*>(
        reinterpret_cast<const char*>(&Klds[buf][0]) + off);
  };
  auto vread = [&](int buf, int row, int kbyte) -> bf16x8 {
    const int off = row * 128 + (kbyte ^ ((row & 7) << 4));
    return *reinterpret_cast<const bf16x8*>(
        reinterpret_cast<const char*>(&Vlds[buf][0]) + off);
  };

  f32x4 oacc[4] = {};
  float mrun[4] = {-1e30f, -1e30f, -1e30f, -1e30f};
  float lrun[4] = {0.f, 0.f, 0.f, 0.f};

  stage(0, 0);
  __syncthreads();

  for (int kb = 0; kb < SEQ / 64; ++kb) {
    const int cur = kb & 1;
    if (kb + 1 < SEQ / 64) stage(cur ^ 1, kb + 1);

    // scores: S[16 q][64 kc] per wave
    f32x4 s[4];
#pragma unroll
    for (int nt = 0; nt < 4; ++nt) {
      bf16x8 kf0 = kread(cur, nt * 16 + lr, lg * 16);
      bf16x8 kf1 = kread(cur, nt * 16 + lr, 64 + lg * 16);
      f32x4 a = {};
      a = __builtin_amdgcn_mfma_f32_16x16x32_bf16(qf[0], kf0, a, 0, 0, 0);
      a = __builtin_amdgcn_mfma_f32_16x16x32_bf16(qf[1], kf1, a, 0, 0, 0);
      s[nt] = a * 0.125f;  // 1/sqrt(64)
    }

    // online softmax (row = lg*4 + r, cols across lr + nt)
    float al[4];
#pragma unroll
    for (int r = 0; r < 4; ++r) {
      float mx = fmaxf(fmaxf(s[0][r], s[1][r]), fmaxf(s[2][r], s[3][r]));
#pragma unroll
      for (int msk = 1; msk < 16; msk <<= 1) mx = fmaxf(mx, __shfl_xor(mx, msk));
      const float mn = fmaxf(mrun[r], mx);
      al[r] = __expf(mrun[r] - mn);
      mrun[r] = mn;
    }
    float rs[4] = {0.f, 0.f, 0.f, 0.f};
#pragma unroll
    for (int nt = 0; nt < 4; ++nt) {
#pragma unroll
      for (int r = 0; r < 4; ++r) {
        const float p = __expf(s[nt][r] - mrun[r]);
        rs[r] += p;
        Plds[w][lg * 4 + r][nt * 16 + lr] = f2bf(p);
      }
    }
#pragma unroll
    for (int r = 0; r < 4; ++r) {
      float t = rs[r];
#pragma unroll
      for (int msk = 1; msk < 16; msk <<= 1) t += __shfl_xor(t, msk);
      lrun[r] = lrun[r] * al[r] + t;
#pragma unroll
      for (int nd = 0; nd < 4; ++nd) oacc[nd][r] *= al[r];
    }

    // PV: O[16 q][64 d] += P[16][64] * Vt^T  (Vt rows = d, cols = kseq)
#pragma unroll
    for (int kk = 0; kk < 2; ++kk) {
      bf16x8 pa = *reinterpret_cast<const bf16x8*>(&Plds[w][lr][kk * 32 + lg * 8]);
#pragma unroll
      for (int nd = 0; nd < 4; ++nd) {
        bf16x8 vf = vread(cur, nd * 16 + lr, kk * 64 + lg * 16);
        oacc[nd] = __builtin_amdgcn_mfma_f32_16x16x32_bf16(pa, vf, oacc[nd], 0, 0, 0);
      }
    }
    __syncthreads();
  }

#pragma unroll
  for (int r = 0; r < 4; ++r) {
    const float inv = 1.f / lrun[r];
    const size_t qrow = (size_t)(qb * 64 + w * 16 + lg * 4 + r) * DM;
#pragma unroll
    for (int nd = 0; nd < 4; ++nd)
      attn_out[qrow + h * 64 + nd * 16 + lr] = f2bf(oacc[nd][r] * inv);
  }
}

// ---------------- in-place row LayerNorm ----------------
__global__ __launch_bounds__(256)
void k_ln(float* __restrict__ x, const float* __restrict__ gamma,
          const float* __restrict__ beta) {
  const int row = blockIdx.x, tid = threadIdx.x;
  float4 v = reinterpret_cast<const float4*>(x + (size_t)row * DM)[tid];
  float s = v.x + v.y + v.z + v.w;
  float q = v.x * v.x + v.y * v.y + v.z * v.z + v.w * v.w;
#pragma unroll
  for (int m = 1; m < 64; m <<= 1) { s += __shfl_xor(s, m); q += __shfl_xor(q, m); }
  __shared__ float sh[8];
  const int w = tid >> 6;
  if ((tid & 63) == 0) { sh[w] = s; sh[4 + w] = q; }
  __syncthreads();
  s = sh[0] + sh[1] + sh[2] + sh[3];
  q = sh[4] + sh[5] + sh[6] + sh[7];
  const float mu = s * (1.f / 1024.f);
  const float var = q * (1.f / 1024.f) - mu * mu;
  const float rstd = rsqrtf(var + LN_EPS);
  float4 g = reinterpret_cast<const float4*>(gamma)[tid];
  float4 b = reinterpret_cast<const float4*>(beta)[tid];
  float4 o;
  o.x = (v.x - mu) * rstd * g.x + b.x;
  o.y = (v.y - mu) * rstd * g.y + b.y;
  o.z = (v.z - mu) * rstd * g.z + b.z;
  o.w = (v.w - mu) * rstd * g.w + b.w;
  reinterpret_cast<float4*>(x + (size_t)row * DM)[tid] = o;
}

extern "C" void kernel_launch(void* const* d_in, const int* in_sizes, int n_in,
                              void* d_out, int out_size, void* d_ws, size_t ws_size,
                              hipStream_t stream) {
  const float* h     = (const float*)d_in[0];
  const float* Wqkv  = (const float*)d_in[1];
  const float* bqkv  = (const float*)d_in[2];
  const float* Wout  = (const float*)d_in[3];
  const float* bout  = (const float*)d_in[4];
  const float* gamma = (const float*)d_in[5];
  const float* beta  = (const float*)d_in[6];
  float* out = (float*)d_out;

  char* ws = (char*)d_ws;
  u16* h_bf    = (u16*)(ws);                             // 4 MB
  u16* Wqkv_bf = (u16*)(ws + (size_t)4 * 1024 * 1024);   // 6 MB
  u16* Wout_bf = (u16*)(ws + (size_t)10 * 1024 * 1024);  // 2 MB
  u16* qk_bf   = (u16*)(ws + (size_t)12 * 1024 * 1024);  // [2048][2048] 8 MB
  u16* vt_bf   = (u16*)(ws + (size_t)20 * 1024 * 1024);  // [1024][2048] 4 MB
  u16* attn_bf = (u16*)(ws + (size_t)24 * 1024 * 1024);  // 4 MB

  k_f2bf<<<2048, 256, 0, stream>>>(h, h_bf, SEQ * DM / 4);
  k_f2bf<<<3072, 256, 0, stream>>>(Wqkv, Wqkv_bf, 3 * DM * DM / 4);
  k_f2bf<<<1024, 256, 0, stream>>>(Wout, Wout_bf, DM * DM / 4);

  k_gemm_bt<2><<<dim3(24, 16), 256, 0, stream>>>(h_bf, Wqkv_bf, bqkv, nullptr,
                                                 qk_bf, vt_bf, nullptr,
                                                 SEQ, 3 * DM, DM);

  k_attn<<<dim3(SEQ / 64, NH), 256, 0, stream>>>(qk_bf, vt_bf, attn_bf);

  k_gemm_bt<1><<<dim3(8, 16), 256, 0, stream>>>(attn_bf, Wout_bf, bout, h,
                                                nullptr, nullptr, out,
                                                SEQ, DM, DM);

  k_ln<<<SEQ, 256, 0, stream>>>(out, gamma, beta);
}

// Round 3
// 119.457 us; speedup vs baseline: 1.3750x; 1.1851x over previous
//
#include <hip/hip_runtime.h>
#include <stdint.h>

#define SEQ 2048
#define DM 1024
#define NH 16
#define DH 64
#define LN_EPS 1e-5f

typedef __bf16 bf16x8 __attribute__((ext_vector_type(8)));
typedef float f32x4 __attribute__((ext_vector_type(4)));
typedef unsigned short u16;
typedef unsigned short u16x8 __attribute__((ext_vector_type(8)));
typedef unsigned int u32;

__device__ __forceinline__ u16 f2bf(float f) {
  unsigned int u = __float_as_uint(f);
  unsigned int r = (u + 0x7fffu + ((u >> 16) & 1u)) >> 16;
  return (u16)r;
}

// pack two f32 -> one u32 of two bf16 (RNE via compiler casts)
__device__ __forceinline__ u32 packbf(float a, float b) {
  union { __bf16 h[2]; u32 u; } pw;
  pw.h[0] = (__bf16)a; pw.h[1] = (__bf16)b;
  return pw.u;
}

#define GLD_LDS16(gp, lp) __builtin_amdgcn_global_load_lds( \
  (const __attribute__((address_space(1))) void*)(gp),      \
  (__attribute__((address_space(3))) void*)(lp), 16, 0, 0)

// ---------------- f32 -> bf16 convert ----------------
__global__ __launch_bounds__(256) void k_f2bf(const float* __restrict__ in,
                                              u16* __restrict__ out, int n4) {
  int i = blockIdx.x * 256 + threadIdx.x;
  if (i >= n4) return;
  float4 v = reinterpret_cast<const float4*>(in)[i];
  ushort4 o;
  o.x = f2bf(v.x); o.y = f2bf(v.y); o.z = f2bf(v.z); o.w = f2bf(v.w);
  reinterpret_cast<ushort4*>(out)[i] = o;
}

// ---------------- GEMM: C = A(bf16 MxK) * B(bf16 NxK)^T + bias ----------------
// BM in {128, 64}; BN fixed 128; 4 waves in 2x2; wave tile (BM/2) x 64.
// EPI 1: outf = res + acc + bias (residual fused).
// EPI 2: QKV split: n<2048 -> outb[m][n] ([M][2048] q|k packed);
//        n>=2048  -> outv[(n-2048)][m] (V transposed, [1024][M]).
template <int EPI, int BM>
__global__ __launch_bounds__(256)
void k_gemm_bt(const u16* __restrict__ A, const u16* __restrict__ B,
               const float* __restrict__ bias, const float* __restrict__ res,
               u16* __restrict__ outb, u16* __restrict__ outv,
               float* __restrict__ outf, int M, int N, int K) {
  constexpr int MF = BM / 32;  // m-frags per wave
  constexpr int WM = BM / 2;   // wave m-tile
  constexpr int AG = BM / 64;  // A-stage GLDs per wave
  __shared__ u16 Alds[2][BM][32];
  __shared__ u16 Blds[2][128][32];
  const int tid = threadIdx.x;
  const int w = tid >> 6, l = tid & 63, lg = l >> 4, lr = l & 15;
  const int wr = w >> 1, wc = w & 1;
  const int m0 = blockIdx.y * BM, n0 = blockIdx.x * 128;
  const int KT = K >> 5;

  f32x4 acc[MF][4] = {};

  auto stage = [&](int buf, int kt) {
    const int k0 = kt << 5;
    const int row = l >> 2, col = (l & 3) * 8;
#pragma unroll
    for (int p = 0; p < AG; ++p) {
      const int rbase = (w * AG + p) * 16;
      GLD_LDS16(A + (size_t)(m0 + rbase + row) * K + k0 + col, &Alds[buf][rbase][0]);
    }
#pragma unroll
    for (int p = 0; p < 2; ++p) {
      const int rbase = (w * 2 + p) * 16;
      GLD_LDS16(B + (size_t)(n0 + rbase + row) * K + k0 + col, &Blds[buf][rbase][0]);
    }
  };

  auto compute = [&](int buf) {
    bf16x8 af[MF], bfr[4];
#pragma unroll
    for (int mi = 0; mi < MF; ++mi)
      af[mi] = *reinterpret_cast<const bf16x8*>(&Alds[buf][wr * WM + mi * 16 + lr][lg * 8]);
#pragma unroll
    for (int ni = 0; ni < 4; ++ni)
      bfr[ni] = *reinterpret_cast<const bf16x8*>(&Blds[buf][wc * 64 + ni * 16 + lr][lg * 8]);
#pragma unroll
    for (int mi = 0; mi < MF; ++mi)
#pragma unroll
      for (int ni = 0; ni < 4; ++ni)
        acc[mi][ni] = __builtin_amdgcn_mfma_f32_16x16x32_bf16(af[mi], bfr[ni], acc[mi][ni], 0, 0, 0);
  };

  stage(0, 0);
  __syncthreads();
  for (int kt = 0; kt < KT; ++kt) {
    const int cur = kt & 1;
    if (kt + 1 < KT) stage(cur ^ 1, kt + 1);
    compute(cur);
    __syncthreads();
  }

  if (EPI == 1) {
#pragma unroll
    for (int ni = 0; ni < 4; ++ni) {
      const int n = n0 + wc * 64 + ni * 16 + lr;
      const float bn = bias[n];
#pragma unroll
      for (int mi = 0; mi < MF; ++mi) {
#pragma unroll
        for (int r = 0; r < 4; ++r) {
          const int m = m0 + wr * WM + mi * 16 + lg * 4 + r;
          outf[(size_t)m * N + n] = res[(size_t)m * N + n] + acc[mi][ni][r] + bn;
        }
      }
    }
  } else {  // EPI == 2
    if (n0 < 2048) {
#pragma unroll
      for (int ni = 0; ni < 4; ++ni) {
        const int n = n0 + wc * 64 + ni * 16 + lr;
        const float bn = bias[n];
#pragma unroll
        for (int mi = 0; mi < MF; ++mi) {
#pragma unroll
          for (int r = 0; r < 4; ++r) {
            const int m = m0 + wr * WM + mi * 16 + lg * 4 + r;
            outb[(size_t)m * 2048 + n] = f2bf(acc[mi][ni][r] + bn);
          }
        }
      }
    } else {
#pragma unroll
      for (int ni = 0; ni < 4; ++ni) {
        const int n = n0 + wc * 64 + ni * 16 + lr;
        const float bn = bias[n];
#pragma unroll
        for (int mi = 0; mi < MF; ++mi) {
          const int mb = m0 + wr * WM + mi * 16 + lg * 4;
          ushort4 pk;
          pk.x = f2bf(acc[mi][ni][0] + bn);
          pk.y = f2bf(acc[mi][ni][1] + bn);
          pk.z = f2bf(acc[mi][ni][2] + bn);
          pk.w = f2bf(acc[mi][ni][3] + bn);
          *reinterpret_cast<ushort4*>(&outv[(size_t)(n - 2048) * M + mb]) = pk;
        }
      }
    }
  }
}

// ---------------- flash attention (swapped QK^T, in-register softmax) --------
// qk: [2048][2048] bf16 (q|k each 1024 cols). vt: [1024][2048] bf16 (V^T).
// out: [2048][1024] bf16.
// Per wave: 16 q rows. Swapped QK: lane l holds S[k=nt*16+lg*4+r][q=lr]
// -> full 64-k P-row per lane-column; softmax reduce = in-reg + 2 shfl.
__global__ __launch_bounds__(256)
void k_attn(const u16* __restrict__ qk, const u16* __restrict__ vt,
            u16* __restrict__ attn_out) {
  __shared__ u16 Klds[2][64 * 64];
  __shared__ u16 Vlds[2][64 * 64];
  __shared__ u16 Plds[4][16][80];  // 160B rows: b128-aligned, conflict-light
  const int tid = threadIdx.x;
  const int w = tid >> 6, l = tid & 63, lg = l >> 4, lr = l & 15;
  const int qb = blockIdx.x, h = blockIdx.y;

  // Q B-fragment: lane holds Q[q=lr][d = half*32 + lg*8 + j]
  bf16x8 qf[2];
  {
    const size_t qrow = (size_t)(qb * 64 + w * 16 + lr) * 2048 + h * 64;
    qf[0] = *reinterpret_cast<const bf16x8*>(&qk[qrow + lg * 8]);
    qf[1] = *reinterpret_cast<const bf16x8*>(&qk[qrow + 32 + lg * 8]);
  }

  // stage: linear LDS dest (global_load_lds), inverse-swizzled global source.
  auto stage = [&](int buf, int kb) {
#pragma unroll
    for (int p = 0; p < 2; ++p) {
      const int r = w * 16 + p * 8 + (l >> 3);
      const int sc = (l & 7) ^ (r & 7);
      const u16* ksrc = qk + (size_t)(kb * 64 + r) * 2048 + 1024 + h * 64 + sc * 8;
      GLD_LDS16(ksrc, &Klds[buf][(w * 16 + p * 8) * 64]);
      const u16* vsrc = vt + (size_t)(h * 64 + r) * 2048 + kb * 64 + sc * 8;
      GLD_LDS16(vsrc, &Vlds[buf][(w * 16 + p * 8) * 64]);
    }
  };

  auto kread = [&](int buf, int row, int kbyte) -> bf16x8 {
    const int off = row * 128 + (kbyte ^ ((row & 7) << 4));
    return *reinterpret_cast<const bf16x8*>(
        reinterpret_cast<const char*>(&Klds[buf][0]) + off);
  };
  auto vread = [&](int buf, int row, int kbyte) -> bf16x8 {
    const int off = row * 128 + (kbyte ^ ((row & 7) << 4));
    return *reinterpret_cast<const bf16x8*>(
        reinterpret_cast<const char*>(&Vlds[buf][0]) + off);
  };

  f32x4 oacc[4] = {};
  float mrun = -1e30f, lrun = 0.f;
  // fold 1/sqrt(64) and log2(e): softmax done in base-2 domain
  const float SC = 0.18033688011112042f;

  stage(0, 0);
  __syncthreads();

  for (int kb = 0; kb < SEQ / 64; ++kb) {
    const int cur = kb & 1;
    if (kb + 1 < SEQ / 64) stage(cur ^ 1, kb + 1);

    // swapped QK^T: S[k][q], lane: q=lr, k = nt*16 + lg*4 + r
    float p[4][4];
    float pmax = -1e30f;
#pragma unroll
    for (int nt = 0; nt < 4; ++nt) {
      bf16x8 kf0 = kread(cur, nt * 16 + lr, lg * 16);
      bf16x8 kf1 = kread(cur, nt * 16 + lr, 64 + lg * 16);
      f32x4 a = {};
      a = __builtin_amdgcn_mfma_f32_16x16x32_bf16(kf0, qf[0], a, 0, 0, 0);
      a = __builtin_amdgcn_mfma_f32_16x16x32_bf16(kf1, qf[1], a, 0, 0, 0);
#pragma unroll
      for (int r = 0; r < 4; ++r) {
        p[nt][r] = a[r] * SC;
        pmax = fmaxf(pmax, p[nt][r]);
      }
    }
    pmax = fmaxf(pmax, __shfl_xor(pmax, 16));
    pmax = fmaxf(pmax, __shfl_xor(pmax, 32));

    // defer-max: only rescale O when tile max grows past threshold (log2 dom)
    if (__any(pmax > mrun + 8.0f)) {
      const float mnew = fmaxf(mrun, pmax);
      const float al = exp2f(mrun - mnew);
      mrun = mnew;
      lrun *= al;
      float alr[4];
#pragma unroll
      for (int r = 0; r < 4; ++r) alr[r] = __shfl(al, lg * 4 + r);
#pragma unroll
      for (int nd = 0; nd < 4; ++nd)
#pragma unroll
        for (int r = 0; r < 4; ++r) oacc[nd][r] *= alr[r];
    }

    float rsum = 0.f;
#pragma unroll
    for (int nt = 0; nt < 4; ++nt)
#pragma unroll
      for (int r = 0; r < 4; ++r) {
        p[nt][r] = exp2f(p[nt][r] - mrun);
        rsum += p[nt][r];
      }
    rsum += __shfl_xor(rsum, 16);
    rsum += __shfl_xor(rsum, 32);
    lrun += rsum;

    // pack P row (q=lr) into bf16 pairs; word w=8nt+2lg+r2 holds k=2w,2w+1
#pragma unroll
    for (int nt = 0; nt < 4; ++nt) {
      uint2 wv;
      wv.x = packbf(p[nt][0], p[nt][1]);
      wv.y = packbf(p[nt][2], p[nt][3]);
      *reinterpret_cast<uint2*>(&Plds[w][lr][16 * nt + 4 * lg]) = wv;
    }

    // PV: O[q][d] += P[q][k] * V[k][d];  A=P frag: lane q=lr, k=kk*32+lg*8+j
#pragma unroll
    for (int kk = 0; kk < 2; ++kk) {
      bf16x8 pa = *reinterpret_cast<const bf16x8*>(&Plds[w][lr][kk * 32 + lg * 8]);
#pragma unroll
      for (int nd = 0; nd < 4; ++nd) {
        bf16x8 vf = vread(cur, nd * 16 + lr, kk * 64 + lg * 16);
        oacc[nd] = __builtin_amdgcn_mfma_f32_16x16x32_bf16(pa, vf, oacc[nd], 0, 0, 0);
      }
    }
    __syncthreads();
  }

  // epilogue: O rows q=lg*4+r need 1/lrun of lane lg*4+r
  float linv[4];
#pragma unroll
  for (int r = 0; r < 4; ++r) linv[r] = 1.f / __shfl(lrun, lg * 4 + r);
#pragma unroll
  for (int r = 0; r < 4; ++r) {
    const size_t qrow = (size_t)(qb * 64 + w * 16 + lg * 4 + r) * DM;
#pragma unroll
    for (int nd = 0; nd < 4; ++nd)
      attn_out[qrow + h * 64 + nd * 16 + lr] = f2bf(oacc[nd][r] * linv[r]);
  }
}

// ---------------- in-place row LayerNorm ----------------
__global__ __launch_bounds__(256)
void k_ln(float* __restrict__ x, const float* __restrict__ gamma,
          const float* __restrict__ beta) {
  const int row = blockIdx.x, tid = threadIdx.x;
  float4 v = reinterpret_cast<const float4*>(x + (size_t)row * DM)[tid];
  float s = v.x + v.y + v.z + v.w;
  float q = v.x * v.x + v.y * v.y + v.z * v.z + v.w * v.w;
#pragma unroll
  for (int m = 1; m < 64; m <<= 1) { s += __shfl_xor(s, m); q += __shfl_xor(q, m); }
  __shared__ float sh[8];
  const int w = tid >> 6;
  if ((tid & 63) == 0) { sh[w] = s; sh[4 + w] = q; }
  __syncthreads();
  s = sh[0] + sh[1] + sh[2] + sh[3];
  q = sh[4] + sh[5] + sh[6] + sh[7];
  const float mu = s * (1.f / 1024.f);
  const float var = q * (1.f / 1024.f) - mu * mu;
  const float rstd = rsqrtf(var + LN_EPS);
  float4 g = reinterpret_cast<const float4*>(gamma)[tid];
  float4 b = reinterpret_cast<const float4*>(beta)[tid];
  float4 o;
  o.x = (v.x - mu) * rstd * g.x + b.x;
  o.y = (v.y - mu) * rstd * g.y + b.y;
  o.z = (v.z - mu) * rstd * g.z + b.z;
  o.w = (v.w - mu) * rstd * g.w + b.w;
  reinterpret_cast<float4*>(x + (size_t)row * DM)[tid] = o;
}

extern "C" void kernel_launch(void* const* d_in, const int* in_sizes, int n_in,
                              void* d_out, int out_size, void* d_ws, size_t ws_size,
                              hipStream_t stream) {
  const float* h     = (const float*)d_in[0];
  const float* Wqkv  = (const float*)d_in[1];
  const float* bqkv  = (const float*)d_in[2];
  const float* Wout  = (const float*)d_in[3];
  const float* bout  = (const float*)d_in[4];
  const float* gamma = (const float*)d_in[5];
  const float* beta  = (const float*)d_in[6];
  float* out = (float*)d_out;

  char* ws = (char*)d_ws;
  u16* h_bf    = (u16*)(ws);                             // 4 MB
  u16* Wqkv_bf = (u16*)(ws + (size_t)4 * 1024 * 1024);   // 6 MB
  u16* Wout_bf = (u16*)(ws + (size_t)10 * 1024 * 1024);  // 2 MB
  u16* qk_bf   = (u16*)(ws + (size_t)12 * 1024 * 1024);  // [2048][2048] 8 MB
  u16* vt_bf   = (u16*)(ws + (size_t)20 * 1024 * 1024);  // [1024][2048] 4 MB
  u16* attn_bf = (u16*)(ws + (size_t)24 * 1024 * 1024);  // 4 MB

  k_f2bf<<<2048, 256, 0, stream>>>(h, h_bf, SEQ * DM / 4);
  k_f2bf<<<3072, 256, 0, stream>>>(Wqkv, Wqkv_bf, 3 * DM * DM / 4);
  k_f2bf<<<1024, 256, 0, stream>>>(Wout, Wout_bf, DM * DM / 4);

  k_gemm_bt<2, 64><<<dim3(24, 32), 256, 0, stream>>>(h_bf, Wqkv_bf, bqkv, nullptr,
                                                     qk_bf, vt_bf, nullptr,
                                                     SEQ, 3 * DM, DM);

  k_attn<<<dim3(SEQ / 64, NH), 256, 0, stream>>>(qk_bf, vt_bf, attn_bf);

  k_gemm_bt<1, 64><<<dim3(8, 32), 256, 0, stream>>>(attn_bf, Wout_bf, bout, h,
                                                    nullptr, nullptr, out,
                                                    SEQ, DM, DM);

  k_ln<<<SEQ, 256, 0, stream>>>(out, gamma, beta);
}

// Round 4
// 110.021 us; speedup vs baseline: 1.4929x; 1.0858x over previous
//
#include <hip/hip_runtime.h>
#include <stdint.h>

#define SEQ 2048
#define DM 1024
#define NH 16
#define DH 64
#define LN_EPS 1e-5f

typedef __bf16 bf16x8 __attribute__((ext_vector_type(8)));
typedef float f32x4 __attribute__((ext_vector_type(4)));
typedef unsigned short u16;
typedef unsigned short u16x8 __attribute__((ext_vector_type(8)));
typedef unsigned int u32;

__device__ __forceinline__ u16 f2bf(float f) {
  unsigned int u = __float_as_uint(f);
  unsigned int r = (u + 0x7fffu + ((u >> 16) & 1u)) >> 16;
  return (u16)r;
}

__device__ __forceinline__ u32 packbf(float a, float b) {
  union { __bf16 h[2]; u32 u; } pw;
  pw.h[0] = (__bf16)a; pw.h[1] = (__bf16)b;
  return pw.u;
}

#define GLD_LDS16(gp, lp) __builtin_amdgcn_global_load_lds( \
  (const __attribute__((address_space(1))) void*)(gp),      \
  (__attribute__((address_space(3))) void*)(lp), 16, 0, 0)

// ---------------- f32 -> bf16 convert ----------------
__global__ __launch_bounds__(256) void k_f2bf(const float* __restrict__ in,
                                              u16* __restrict__ out, int n4) {
  int i = blockIdx.x * 256 + threadIdx.x;
  if (i >= n4) return;
  float4 v = reinterpret_cast<const float4*>(in)[i];
  ushort4 o;
  o.x = f2bf(v.x); o.y = f2bf(v.y); o.z = f2bf(v.z); o.w = f2bf(v.w);
  reinterpret_cast<ushort4*>(out)[i] = o;
}

// ---------------- GEMM: C = A(bf16 MxK) * B(bf16 NxK)^T + bias ----------------
// 4 waves 2x2; wave tile (BM/2)x(BN/2).
// EPI 1: outf = res + acc + bias.
// EPI 2: QKV split: n<2048 -> outb[m][n]; n>=2048 -> outv[(n-2048)][m] (V^T).
template <int EPI, int BM, int BN>
__global__ __launch_bounds__(256)
void k_gemm_bt(const u16* __restrict__ A, const u16* __restrict__ B,
               const float* __restrict__ bias, const float* __restrict__ res,
               u16* __restrict__ outb, u16* __restrict__ outv,
               float* __restrict__ outf, int M, int N, int K) {
  constexpr int MF = BM / 32, NF = BN / 32;
  constexpr int WM = BM / 2, WN = BN / 2;
  constexpr int AG = BM / 64, BG = BN / 64;
  __shared__ u16 Alds[2][BM][32];
  __shared__ u16 Blds[2][BN][32];
  const int tid = threadIdx.x;
  const int w = tid >> 6, l = tid & 63, lg = l >> 4, lr = l & 15;
  const int wr = w >> 1, wc = w & 1;
  const int m0 = blockIdx.y * BM, n0 = blockIdx.x * BN;
  const int KT = K >> 5;

  f32x4 acc[MF][NF] = {};

  auto stage = [&](int buf, int kt) {
    const int k0 = kt << 5;
    const int row = l >> 2, col = (l & 3) * 8;
#pragma unroll
    for (int p = 0; p < AG; ++p) {
      const int rbase = (w * AG + p) * 16;
      GLD_LDS16(A + (size_t)(m0 + rbase + row) * K + k0 + col, &Alds[buf][rbase][0]);
    }
#pragma unroll
    for (int p = 0; p < BG; ++p) {
      const int rbase = (w * BG + p) * 16;
      GLD_LDS16(B + (size_t)(n0 + rbase + row) * K + k0 + col, &Blds[buf][rbase][0]);
    }
  };

  auto compute = [&](int buf) {
    bf16x8 af[MF], bfr[NF];
#pragma unroll
    for (int mi = 0; mi < MF; ++mi)
      af[mi] = *reinterpret_cast<const bf16x8*>(&Alds[buf][wr * WM + mi * 16 + lr][lg * 8]);
#pragma unroll
    for (int ni = 0; ni < NF; ++ni)
      bfr[ni] = *reinterpret_cast<const bf16x8*>(&Blds[buf][wc * WN + ni * 16 + lr][lg * 8]);
#pragma unroll
    for (int mi = 0; mi < MF; ++mi)
#pragma unroll
      for (int ni = 0; ni < NF; ++ni)
        acc[mi][ni] = __builtin_amdgcn_mfma_f32_16x16x32_bf16(af[mi], bfr[ni], acc[mi][ni], 0, 0, 0);
  };

  stage(0, 0);
  __syncthreads();
  for (int kt = 0; kt < KT; ++kt) {
    const int cur = kt & 1;
    if (kt + 1 < KT) stage(cur ^ 1, kt + 1);
    compute(cur);
    __syncthreads();
  }

  if (EPI == 1) {
#pragma unroll
    for (int ni = 0; ni < NF; ++ni) {
      const int n = n0 + wc * WN + ni * 16 + lr;
      const float bn = bias[n];
#pragma unroll
      for (int mi = 0; mi < MF; ++mi) {
#pragma unroll
        for (int r = 0; r < 4; ++r) {
          const int m = m0 + wr * WM + mi * 16 + lg * 4 + r;
          outf[(size_t)m * N + n] = res[(size_t)m * N + n] + acc[mi][ni][r] + bn;
        }
      }
    }
  } else {  // EPI == 2
    if (n0 < 2048) {
#pragma unroll
      for (int ni = 0; ni < NF; ++ni) {
        const int n = n0 + wc * WN + ni * 16 + lr;
        const float bn = bias[n];
#pragma unroll
        for (int mi = 0; mi < MF; ++mi) {
#pragma unroll
          for (int r = 0; r < 4; ++r) {
            const int m = m0 + wr * WM + mi * 16 + lg * 4 + r;
            outb[(size_t)m * 2048 + n] = f2bf(acc[mi][ni][r] + bn);
          }
        }
      }
    } else {
#pragma unroll
      for (int ni = 0; ni < NF; ++ni) {
        const int n = n0 + wc * WN + ni * 16 + lr;
        const float bn = bias[n];
#pragma unroll
        for (int mi = 0; mi < MF; ++mi) {
          const int mb = m0 + wr * WM + mi * 16 + lg * 4;
          ushort4 pk;
          pk.x = f2bf(acc[mi][ni][0] + bn);
          pk.y = f2bf(acc[mi][ni][1] + bn);
          pk.z = f2bf(acc[mi][ni][2] + bn);
          pk.w = f2bf(acc[mi][ni][3] + bn);
          *reinterpret_cast<ushort4*>(&outv[(size_t)(n - 2048) * M + mb]) = pk;
        }
      }
    }
  }
}

// ---------------- flash attention, KV-split ----------------
// qk: [2048][2048] bf16 (q|k). vt: [1024][2048] bf16 (V^T).
// Opart: [KSPLIT][2048][1024] f32 (unnormalized). ml: [KSPLIT][16][2048] float2.
template <int KSPLIT>
__global__ __launch_bounds__(256)
void k_attn(const u16* __restrict__ qk, const u16* __restrict__ vt,
            float* __restrict__ Opart, float2* __restrict__ ml) {
  __shared__ u16 Klds[2][64 * 64];
  __shared__ u16 Vlds[2][64 * 64];
  __shared__ u16 Plds[4][16 * 64];  // XOR-swizzled, per-wave
  const int tid = threadIdx.x;
  const int w = tid >> 6, l = tid & 63, lg = l >> 4, lr = l & 15;
  const int qb = blockIdx.x, h = blockIdx.y, sp = blockIdx.z;
  constexpr int NTILES = (SEQ / 64) / KSPLIT;
  const int kb0 = sp * NTILES;

  // Q B-fragment: lane holds Q[q=lr][d = half*32 + lg*8 + j]
  bf16x8 qf[2];
  {
    const size_t qrow = (size_t)(qb * 64 + w * 16 + lr) * 2048 + h * 64;
    qf[0] = *reinterpret_cast<const bf16x8*>(&qk[qrow + lg * 8]);
    qf[1] = *reinterpret_cast<const bf16x8*>(&qk[qrow + 32 + lg * 8]);
  }

  // per-lane staging source bases (inverse-swizzled global, linear LDS dest)
  const int sr0 = w * 16 + (l >> 3);        // p=0 row
  const int sc0 = ((l & 7) ^ (sr0 & 7)) * 8;
  const int sr1 = sr0 + 8;                  // p=1 row
  const int sc1 = ((l & 7) ^ (sr1 & 7)) * 8;
  const u16* kb_base = qk + 1024 + h * 64;
  const u16* vb_base = vt + (size_t)(h * 64) * 2048;

  auto stage = [&](int buf, int kb) {
    const u16* k0 = kb_base + (size_t)(kb * 64 + sr0) * 2048 + sc0;
    const u16* k1 = kb_base + (size_t)(kb * 64 + sr1) * 2048 + sc1;
    const u16* v0 = vb_base + (size_t)sr0 * 2048 + kb * 64 + sc0;
    const u16* v1 = vb_base + (size_t)sr1 * 2048 + kb * 64 + sc1;
    GLD_LDS16(k0, &Klds[buf][(w * 16) * 64]);
    GLD_LDS16(k1, &Klds[buf][(w * 16 + 8) * 64]);
    GLD_LDS16(v0, &Vlds[buf][(w * 16) * 64]);
    GLD_LDS16(v1, &Vlds[buf][(w * 16 + 8) * 64]);
  };

  auto kread = [&](int buf, int row, int kbyte) -> bf16x8 {
    const int off = row * 128 + (kbyte ^ ((row & 7) << 4));
    return *reinterpret_cast<const bf16x8*>(
        reinterpret_cast<const char*>(&Klds[buf][0]) + off);
  };
  auto vread = [&](int buf, int row, int kbyte) -> bf16x8 {
    const int off = row * 128 + (kbyte ^ ((row & 7) << 4));
    return *reinterpret_cast<const bf16x8*>(
        reinterpret_cast<const char*>(&Vlds[buf][0]) + off);
  };

  f32x4 oacc[4] = {};
  float mrun = -1e30f, lrun = 0.f;
  const float SC = 0.18033688011112042f;  // log2(e)/8

  stage(0, kb0);
  __syncthreads();

  for (int kt = 0; kt < NTILES; ++kt) {
    const int kb = kb0 + kt;
    const int cur = kt & 1;
    if (kt + 1 < NTILES) stage(cur ^ 1, kb + 1);

    // swapped QK^T: lane: q=lr, k = nt*16 + lg*4 + r
    float p[4][4];
    float pmax = -1e30f;
    __builtin_amdgcn_s_setprio(1);
#pragma unroll
    for (int nt = 0; nt < 4; ++nt) {
      bf16x8 kf0 = kread(cur, nt * 16 + lr, lg * 16);
      bf16x8 kf1 = kread(cur, nt * 16 + lr, 64 + lg * 16);
      f32x4 a = {};
      a = __builtin_amdgcn_mfma_f32_16x16x32_bf16(kf0, qf[0], a, 0, 0, 0);
      a = __builtin_amdgcn_mfma_f32_16x16x32_bf16(kf1, qf[1], a, 0, 0, 0);
#pragma unroll
      for (int r = 0; r < 4; ++r) {
        p[nt][r] = a[r] * SC;
        pmax = fmaxf(pmax, p[nt][r]);
      }
    }
    __builtin_amdgcn_s_setprio(0);
    pmax = fmaxf(pmax, __shfl_xor(pmax, 16));
    pmax = fmaxf(pmax, __shfl_xor(pmax, 32));

    // defer-max (threshold 8 in log2 domain)
    if (__any(pmax > mrun + 8.0f)) {
      const float mnew = fmaxf(mrun, pmax);
      const float al = exp2f(mrun - mnew);
      mrun = mnew;
      lrun *= al;
      float alr[4];
#pragma unroll
      for (int r = 0; r < 4; ++r) alr[r] = __shfl(al, lg * 4 + r);
#pragma unroll
      for (int nd = 0; nd < 4; ++nd)
#pragma unroll
        for (int r = 0; r < 4; ++r) oacc[nd][r] *= alr[r];
    }

    float rsum = 0.f;
#pragma unroll
    for (int nt = 0; nt < 4; ++nt)
#pragma unroll
      for (int r = 0; r < 4; ++r) {
        p[nt][r] = exp2f(p[nt][r] - mrun);
        rsum += p[nt][r];
      }
    rsum += __shfl_xor(rsum, 16);
    rsum += __shfl_xor(rsum, 32);
    lrun += rsum;

    // pack P (row q=lr, swizzled): logical bytes 32nt+8lg hold k=nt*16+lg*4..+3
#pragma unroll
    for (int nt = 0; nt < 4; ++nt) {
      uint2 wv;
      wv.x = packbf(p[nt][0], p[nt][1]);
      wv.y = packbf(p[nt][2], p[nt][3]);
      const int pbyte = lr * 128 + ((nt * 32 + lg * 8) ^ ((lr & 7) << 4));
      *reinterpret_cast<uint2*>(reinterpret_cast<char*>(&Plds[w][0]) + pbyte) = wv;
    }

    // PV: O[q][d] += P[q][k] * V[k][d]
    __builtin_amdgcn_s_setprio(1);
#pragma unroll
    for (int kk = 0; kk < 2; ++kk) {
      const int abyte = lr * 128 + ((kk * 64 + lg * 16) ^ ((lr & 7) << 4));
      bf16x8 pa = *reinterpret_cast<const bf16x8*>(
          reinterpret_cast<const char*>(&Plds[w][0]) + abyte);
#pragma unroll
      for (int nd = 0; nd < 4; ++nd) {
        bf16x8 vf = vread(cur, nd * 16 + lr, kk * 64 + lg * 16);
        oacc[nd] = __builtin_amdgcn_mfma_f32_16x16x32_bf16(pa, vf, oacc[nd], 0, 0, 0);
      }
    }
    __builtin_amdgcn_s_setprio(0);
    __syncthreads();
  }

  // epilogue: store unnormalized O + (m, l) per q row
#pragma unroll
  for (int r = 0; r < 4; ++r) {
    const size_t orow = (size_t)sp * SEQ * DM +
                        (size_t)(qb * 64 + w * 16 + lg * 4 + r) * DM + h * 64;
#pragma unroll
    for (int nd = 0; nd < 4; ++nd)
      Opart[orow + nd * 16 + lr] = oacc[nd][r];
  }
  if (lg == 0)
    ml[((size_t)sp * NH + h) * SEQ + qb * 64 + w * 16 + lr] =
        make_float2(mrun, lrun);
}

// ---------------- combine KV-splits ----------------
__global__ __launch_bounds__(256)
void k_combine(const float* __restrict__ Opart, const float2* __restrict__ ml,
               u16* __restrict__ attn_out) {
  const int row = blockIdx.x, tid = threadIdx.x;
  const int h = tid >> 4;  // (tid*4)/64
  const float2 a = ml[(size_t)h * SEQ + row];
  const float2 b = ml[((size_t)NH + h) * SEQ + row];
  const float M = fmaxf(a.x, b.x);
  const float w0 = exp2f(a.x - M), w1 = exp2f(b.x - M);
  const float inv = 1.f / (a.y * w0 + b.y * w1);
  const float4 o0 = reinterpret_cast<const float4*>(Opart + (size_t)row * DM)[tid];
  const float4 o1 = reinterpret_cast<const float4*>(Opart + (size_t)(SEQ + row) * DM)[tid];
  ushort4 pk;
  pk.x = f2bf((o0.x * w0 + o1.x * w1) * inv);
  pk.y = f2bf((o0.y * w0 + o1.y * w1) * inv);
  pk.z = f2bf((o0.z * w0 + o1.z * w1) * inv);
  pk.w = f2bf((o0.w * w0 + o1.w * w1) * inv);
  reinterpret_cast<ushort4*>(attn_out + (size_t)row * DM)[tid] = pk;
}

// ---------------- in-place row LayerNorm ----------------
__global__ __launch_bounds__(256)
void k_ln(float* __restrict__ x, const float* __restrict__ gamma,
          const float* __restrict__ beta) {
  const int row = blockIdx.x, tid = threadIdx.x;
  float4 v = reinterpret_cast<const float4*>(x + (size_t)row * DM)[tid];
  float s = v.x + v.y + v.z + v.w;
  float q = v.x * v.x + v.y * v.y + v.z * v.z + v.w * v.w;
#pragma unroll
  for (int m = 1; m < 64; m <<= 1) { s += __shfl_xor(s, m); q += __shfl_xor(q, m); }
  __shared__ float sh[8];
  const int w = tid >> 6;
  if ((tid & 63) == 0) { sh[w] = s; sh[4 + w] = q; }
  __syncthreads();
  s = sh[0] + sh[1] + sh[2] + sh[3];
  q = sh[4] + sh[5] + sh[6] + sh[7];
  const float mu = s * (1.f / 1024.f);
  const float var = q * (1.f / 1024.f) - mu * mu;
  const float rstd = rsqrtf(var + LN_EPS);
  float4 g = reinterpret_cast<const float4*>(gamma)[tid];
  float4 b = reinterpret_cast<const float4*>(beta)[tid];
  float4 o;
  o.x = (v.x - mu) * rstd * g.x + b.x;
  o.y = (v.y - mu) * rstd * g.y + b.y;
  o.z = (v.z - mu) * rstd * g.z + b.z;
  o.w = (v.w - mu) * rstd * g.w + b.w;
  reinterpret_cast<float4*>(x + (size_t)row * DM)[tid] = o;
}

extern "C" void kernel_launch(void* const* d_in, const int* in_sizes, int n_in,
                              void* d_out, int out_size, void* d_ws, size_t ws_size,
                              hipStream_t stream) {
  const float* h     = (const float*)d_in[0];
  const float* Wqkv  = (const float*)d_in[1];
  const float* bqkv  = (const float*)d_in[2];
  const float* Wout  = (const float*)d_in[3];
  const float* bout  = (const float*)d_in[4];
  const float* gamma = (const float*)d_in[5];
  const float* beta  = (const float*)d_in[6];
  float* out = (float*)d_out;

  char* ws = (char*)d_ws;
  u16* h_bf      = (u16*)(ws);                             // 4 MB
  u16* Wqkv_bf   = (u16*)(ws + (size_t)4 * 1024 * 1024);   // 6 MB
  u16* Wout_bf   = (u16*)(ws + (size_t)10 * 1024 * 1024);  // 2 MB
  u16* qk_bf     = (u16*)(ws + (size_t)12 * 1024 * 1024);  // 8 MB
  u16* vt_bf     = (u16*)(ws + (size_t)20 * 1024 * 1024);  // 4 MB
  u16* attn_bf   = (u16*)(ws + (size_t)24 * 1024 * 1024);  // 4 MB
  float* Opart   = (float*)(ws + (size_t)28 * 1024 * 1024); // 16 MB
  float2* mlbuf  = (float2*)(ws + (size_t)44 * 1024 * 1024); // 0.5 MB

  k_f2bf<<<2048, 256, 0, stream>>>(h, h_bf, SEQ * DM / 4);
  k_f2bf<<<3072, 256, 0, stream>>>(Wqkv, Wqkv_bf, 3 * DM * DM / 4);
  k_f2bf<<<1024, 256, 0, stream>>>(Wout, Wout_bf, DM * DM / 4);

  k_gemm_bt<2, 64, 128><<<dim3(24, 32), 256, 0, stream>>>(
      h_bf, Wqkv_bf, bqkv, nullptr, qk_bf, vt_bf, nullptr, SEQ, 3 * DM, DM);

  k_attn<2><<<dim3(SEQ / 64, NH, 2), 256, 0, stream>>>(qk_bf, vt_bf, Opart, mlbuf);
  k_combine<<<SEQ, 256, 0, stream>>>(Opart, mlbuf, attn_bf);

  k_gemm_bt<1, 64, 64><<<dim3(16, 32), 256, 0, stream>>>(
      attn_bf, Wout_bf, bout, h, nullptr, nullptr, out, SEQ, DM, DM);

  k_ln<<<SEQ, 256, 0, stream>>>(out, gamma, beta);
}